// Round 11
// baseline (3509.034 us; speedup 1.0000x reference)
//
#include <hip/hip_runtime.h>
#include <hip/hip_bf16.h>

#define BATCH 64
#define TSEQ 2048
#define INF 9
#define H 128
#define G4 512
#define NFC 20
#define CH 32                 // pipeline chunk (timesteps)
#define NCH (TSEQ / CH)       // 64 chunks

__device__ __forceinline__ float sigf(float x) {
    return 1.0f / (1.0f + __expf(-x));
}
__device__ __forceinline__ float tanh_fast(float x) {
    // tanh(x) = 1 - 2/(e^{2x}+1); saturates correctly at +/-inf
    return 1.0f - 2.0f / (__expf(2.0f * x) + 1.0f);
}

// ---------------- flag helpers (agent scope, chunk-granular) ----------------
__device__ __forceinline__ void flag_release(int* f) {
    if (threadIdx.x == 0) {
        __threadfence();
        __hip_atomic_store(f, 1, __ATOMIC_RELEASE, __HIP_MEMORY_SCOPE_AGENT);
    }
}
__device__ __forceinline__ void flag_acquire(int* f) {
    if (threadIdx.x == 0) {
        while (__hip_atomic_load(f, __ATOMIC_ACQUIRE, __HIP_MEMORY_SCOPE_AGENT) == 0)
            __builtin_amdgcn_s_sleep(2);
        __threadfence();
    }
    __syncthreads();
}

__global__ __launch_bounds__(512) void zero_flags(int* flags, int n) {
    int i = blockIdx.x * 512 + threadIdx.x;
    for (; i < n; i += gridDim.x * 512) flags[i] = 0;
}

// ================= fused 3-stage ring pipeline =================
// blocks [0,64):   A = lstm0 scan (batch row b) -> h0ring
// blocks [64,128): B = xg1 gemv  (batch row b)  h0ring -> xgring
// blocks [128,192):C = lstm1 scan + head        xgring -> out
__global__ __launch_bounds__(512) void lstm_fused(
    const float* __restrict__ x,
    const float* __restrict__ Wih0, const float* __restrict__ Whh0,
    const float* __restrict__ bih0, const float* __restrict__ bhh0,
    const float* __restrict__ Wih1, const float* __restrict__ Whh1,
    const float* __restrict__ bih1, const float* __restrict__ bhh1,
    const float* __restrict__ fc1w, const float* __restrict__ fc1b,
    const float* __restrict__ fc2w, const float* __restrict__ fc2b,
    float* __restrict__ h0ring, float* __restrict__ xgring,
    int* __restrict__ fA, int* __restrict__ fAfree,
    int* __restrict__ fB, int* __restrict__ fBfree,
    int R, float* __restrict__ out)
{
    __shared__ float hs[H];
    __shared__ float gates[G4];
    __shared__ float hsB4[4][H];
    __shared__ float hbuf[64][132];
    __shared__ float fc1w_s[NFC * 132];
    __shared__ float hfcb[64 * NFC];
    __shared__ float fc2w_s[NFC];
    __shared__ float fc1b_s[NFC];

    const int role = blockIdx.x >> 6;
    const int b    = blockIdx.x & 63;
    const int g    = threadIdx.x;

    if (role == 0) {
        // ---------------- A: layer-0 scan (R4-verified body) ----------------
        float wih[INF], whh[H];
#pragma unroll
        for (int k = 0; k < INF; k++) wih[k] = Wih0[(size_t)g * INF + k];
        const float4* W4 = (const float4*)(Whh0 + (size_t)g * H);
#pragma unroll
        for (int k4 = 0; k4 < H / 4; k4++) {
            float4 wv = W4[k4];
            whh[4 * k4 + 0] = wv.x; whh[4 * k4 + 1] = wv.y;
            whh[4 * k4 + 2] = wv.z; whh[4 * k4 + 3] = wv.w;
        }
        const float bias = bih0[g] + bhh0[g];

        float c = 0.f;
        if (g < H) hs[g] = 0.f;

        const float* xb = x + (size_t)b * TSEQ * INF;
        float xr[INF];
#pragma unroll
        for (int k = 0; k < INF; k++) xr[k] = xb[k];
        __syncthreads();

        for (int ci = 0; ci < NCH; ci++) {
            if (ci >= R) flag_acquire(&fAfree[b * NCH + ci - R]);
            const int slot = ci % R;
            float* h0s = h0ring + ((size_t)slot * BATCH + b) * CH * H;

            for (int tt = 0; tt < CH; tt++) {
                const int t = ci * CH + tt;
                float a0 = bias, a1 = 0.f, a2 = 0.f, a3 = 0.f;
#pragma unroll
                for (int k = 0; k < INF; k++) a0 += wih[k] * xr[k];
                if (t + 1 < TSEQ) {
                    const float* xn = xb + (size_t)(t + 1) * INF;
#pragma unroll
                    for (int k = 0; k < INF; k++) xr[k] = xn[k];
                }
                const float4* h4 = (const float4*)hs;
#pragma unroll
                for (int k4 = 0; k4 < H / 4; k4++) {
                    float4 hv = h4[k4];
                    a0 += whh[4 * k4 + 0] * hv.x;
                    a1 += whh[4 * k4 + 1] * hv.y;
                    a2 += whh[4 * k4 + 2] * hv.z;
                    a3 += whh[4 * k4 + 3] * hv.w;
                }
                gates[g] = (a0 + a1) + (a2 + a3);
                __syncthreads();
                if (g < H) {
                    float ig = sigf(gates[g]);
                    float fg = sigf(gates[H + g]);
                    float gg = tanh_fast(gates[2 * H + g]);
                    float og = sigf(gates[3 * H + g]);
                    c = fg * c + ig * gg;
                    float h = og * tanh_fast(c);
                    hs[g] = h;
                    h0s[(size_t)tt * H + g] = h;
                }
                __syncthreads();
            }
            flag_release(&fA[b * NCH + ci]);
        }
    } else if (role == 1) {
        // ------- B: xg = h0 @ Wih1^T + bias; 4 timesteps per weight pass -------
        const float bias = bih1[g] + bhh1[g];
        const float4* W4 = (const float4*)(Wih1 + (size_t)g * H);

        for (int ci = 0; ci < NCH; ci++) {
            flag_acquire(&fA[b * NCH + ci]);
            if (ci >= R) flag_acquire(&fBfree[b * NCH + ci - R]);
            const int slot = ci % R;
            const float* h0s = h0ring + ((size_t)slot * BATCH + b) * CH * H;
            float* xgs = xgring + ((size_t)slot * BATCH + b) * CH * G4;

            for (int q = 0; q < CH / 4; q++) {
                const int tt = 4 * q;
                // stage 4 timestep rows: thread g stages element (g>>7, g&127)
                {
                    int r = g >> 7;
                    int k = g & 127;
                    hsB4[r][k] = h0s[(size_t)(tt + r) * H + k];
                }
                __syncthreads();
                float a0[4], a1[4], a2[4], a3[4];
#pragma unroll
                for (int r = 0; r < 4; r++) { a0[r] = bias; a1[r] = 0.f; a2[r] = 0.f; a3[r] = 0.f; }
#pragma unroll
                for (int k4 = 0; k4 < H / 4; k4++) {
                    float4 wv = W4[k4];     // streamed once, serves 4 timesteps
#pragma unroll
                    for (int r = 0; r < 4; r++) {
                        float4 hv = ((const float4*)hsB4[r])[k4];
                        a0[r] += wv.x * hv.x; a1[r] += wv.y * hv.y;
                        a2[r] += wv.z * hv.z; a3[r] += wv.w * hv.w;
                    }
                }
#pragma unroll
                for (int r = 0; r < 4; r++)
                    xgs[(size_t)(tt + r) * G4 + g] = (a0[r] + a1[r]) + (a2[r] + a3[r]);
                __syncthreads();
            }
            flag_release(&fB[b * NCH + ci]);       // consumer-critical first
            flag_release(&fAfree[b * NCH + ci]);
        }
    } else {
        // ---------------- C: layer-1 scan + fused head (R4-verified body) ----------------
        float whh[H];
        const float4* W4 = (const float4*)(Whh1 + (size_t)g * H);
#pragma unroll
        for (int k4 = 0; k4 < H / 4; k4++) {
            float4 wv = W4[k4];
            whh[4 * k4 + 0] = wv.x; whh[4 * k4 + 1] = wv.y;
            whh[4 * k4 + 2] = wv.z; whh[4 * k4 + 3] = wv.w;
        }
        for (int i = g; i < NFC * H; i += 512) {
            int r = i >> 7, cidx = i & 127;
            fc1w_s[r * 132 + cidx] = fc1w[i];
        }
        if (g < NFC) { fc2w_s[g] = fc2w[g]; fc1b_s[g] = fc1b[g]; }

        float c = 0.f, h = 0.f;
        if (g < H) hs[g] = 0.f;
        const float fc2bias = fc2b[0];
        __syncthreads();

        for (int ci = 0; ci < NCH; ci++) {
            flag_acquire(&fB[b * NCH + ci]);
            const int slot = ci % R;
            const float* xgs = xgring + ((size_t)slot * BATCH + b) * CH * G4;
            float xgr = xgs[g];

            for (int tt = 0; tt < CH; tt++) {
                const int gt = ci * CH + tt;   // global timestep
                float a0 = xgr, a1 = 0.f, a2 = 0.f, a3 = 0.f;
                if (tt + 1 < CH) xgr = xgs[(size_t)(tt + 1) * G4 + g];
                const float4* h4 = (const float4*)hs;
#pragma unroll
                for (int k4 = 0; k4 < H / 4; k4++) {
                    float4 hv = h4[k4];
                    a0 += whh[4 * k4 + 0] * hv.x;
                    a1 += whh[4 * k4 + 1] * hv.y;
                    a2 += whh[4 * k4 + 2] * hv.z;
                    a3 += whh[4 * k4 + 3] * hv.w;
                }
                gates[g] = (a0 + a1) + (a2 + a3);
                __syncthreads();
                if (g < H) {
                    float ig = sigf(gates[g]);
                    float fg = sigf(gates[H + g]);
                    float gg = tanh_fast(gates[2 * H + g]);
                    float og = sigf(gates[3 * H + g]);
                    c = fg * c + ig * gg;
                    h = og * tanh_fast(c);
                    hs[g] = h;
                    hbuf[gt & 63][g] = h;
                }
                __syncthreads();

                if ((gt & 63) == 63) {
                    // batched head over the last 64 global timesteps
#pragma unroll
                    for (int p = 0; p < 3; p++) {
                        int task = p * 512 + g;
                        if (task < 64 * NFC) {
                            int sidx = task / NFC;
                            int k = task - sidx * NFC;
                            float b0 = fc1b_s[k], b1 = 0.f, b2 = 0.f, b3 = 0.f;
                            const float4* hr = (const float4*)(&hbuf[sidx][0]);
                            const float4* wr = (const float4*)(&fc1w_s[k * 132]);
#pragma unroll
                            for (int k4 = 0; k4 < H / 4; k4++) {
                                float4 hv = hr[k4];
                                float4 wv = wr[k4];
                                b0 += wv.x * hv.x; b1 += wv.y * hv.y;
                                b2 += wv.z * hv.z; b3 += wv.w * hv.w;
                            }
                            hfcb[task] = tanh_fast((b0 + b1) + (b2 + b3));
                        }
                    }
                    __syncthreads();
                    if (g < 64) {
                        float o = fc2bias;
#pragma unroll
                        for (int k = 0; k < NFC; k++) o += fc2w_s[k] * hfcb[g * NFC + k];
                        out[(size_t)b * TSEQ + gt - 63 + g] = o;
                    }
                    __syncthreads();
                }
            }
            flag_release(&fBfree[b * NCH + ci]);
        }
    }
}

// ================= fallback (verified R4 three-kernel path) =================
__global__ __launch_bounds__(512, 2) void lstm0_scan(
    const float* __restrict__ x, const float* __restrict__ Wih,
    const float* __restrict__ Whh, const float* __restrict__ bih,
    const float* __restrict__ bhh, float* __restrict__ h0out)
{
    const int b = blockIdx.x;
    const int g = threadIdx.x;
    __shared__ float hs[H];
    __shared__ float gates[G4];
    float wih[INF], whh[H];
#pragma unroll
    for (int k = 0; k < INF; k++) wih[k] = Wih[(size_t)g * INF + k];
    const float4* W4 = (const float4*)(Whh + (size_t)g * H);
#pragma unroll
    for (int k4 = 0; k4 < H / 4; k4++) {
        float4 wv = W4[k4];
        whh[4 * k4 + 0] = wv.x; whh[4 * k4 + 1] = wv.y;
        whh[4 * k4 + 2] = wv.z; whh[4 * k4 + 3] = wv.w;
    }
    const float bias = bih[g] + bhh[g];
    float c = 0.f;
    if (g < H) hs[g] = 0.f;
    const float* xb = x + (size_t)b * TSEQ * INF;
    float xr[INF];
#pragma unroll
    for (int k = 0; k < INF; k++) xr[k] = xb[k];
    __syncthreads();
    for (int t = 0; t < TSEQ; t++) {
        float a0 = bias, a1 = 0.f, a2 = 0.f, a3 = 0.f;
#pragma unroll
        for (int k = 0; k < INF; k++) a0 += wih[k] * xr[k];
        if (t + 1 < TSEQ) {
            const float* xn = xb + (size_t)(t + 1) * INF;
#pragma unroll
            for (int k = 0; k < INF; k++) xr[k] = xn[k];
        }
        const float4* h4 = (const float4*)hs;
#pragma unroll
        for (int k4 = 0; k4 < H / 4; k4++) {
            float4 hv = h4[k4];
            a0 += whh[4 * k4 + 0] * hv.x;
            a1 += whh[4 * k4 + 1] * hv.y;
            a2 += whh[4 * k4 + 2] * hv.z;
            a3 += whh[4 * k4 + 3] * hv.w;
        }
        gates[g] = (a0 + a1) + (a2 + a3);
        __syncthreads();
        if (g < H) {
            float ig = sigf(gates[g]);
            float fg = sigf(gates[H + g]);
            float gg = tanh_fast(gates[2 * H + g]);
            float og = sigf(gates[3 * H + g]);
            c = fg * c + ig * gg;
            float h = og * tanh_fast(c);
            hs[g] = h;
            h0out[((size_t)b * TSEQ + t) * H + g] = h;
        }
        __syncthreads();
    }
}

__global__ __launch_bounds__(512, 2) void xg1_gemm(
    const float* __restrict__ h0, const float* __restrict__ Wih1,
    const float* __restrict__ bih, const float* __restrict__ bhh,
    float* __restrict__ xg1, int t0, int tlen)
{
    const int b = blockIdx.x >> 2;
    const int s = blockIdx.x & 3;
    const int g = threadIdx.x;
    const int rows = tlen >> 2;
    const int tstart = t0 + s * rows;
    float w[H];
    const float4* W4 = (const float4*)(Wih1 + (size_t)g * H);
#pragma unroll
    for (int k4 = 0; k4 < H / 4; k4++) {
        float4 wv = W4[k4];
        w[4 * k4 + 0] = wv.x; w[4 * k4 + 1] = wv.y;
        w[4 * k4 + 2] = wv.z; w[4 * k4 + 3] = wv.w;
    }
    const float bias = bih[g] + bhh[g];
    __shared__ float hs[2][H];
    if (g < H) hs[0][g] = h0[((size_t)b * TSEQ + tstart) * H + g];
    __syncthreads();
    for (int r = 0; r < rows; r++) {
        int buf = r & 1;
        if (g < H && (r + 1) < rows)
            hs[buf ^ 1][g] = h0[((size_t)b * TSEQ + tstart + r + 1) * H + g];
        float a0 = bias, a1 = 0.f, a2 = 0.f, a3 = 0.f;
        const float4* h4 = (const float4*)hs[buf];
#pragma unroll
        for (int k4 = 0; k4 < H / 4; k4++) {
            float4 hv = h4[k4];
            a0 += w[4 * k4 + 0] * hv.x;
            a1 += w[4 * k4 + 1] * hv.y;
            a2 += w[4 * k4 + 2] * hv.z;
            a3 += w[4 * k4 + 3] * hv.w;
        }
        xg1[((size_t)b * tlen + (size_t)(s * rows + r)) * G4 + g] = (a0 + a1) + (a2 + a3);
        __syncthreads();
    }
}

__global__ __launch_bounds__(512, 2) void lstm1_scan(
    const float* __restrict__ Whh1, const float* __restrict__ xg1,
    const float* __restrict__ fc1w, const float* __restrict__ fc1b,
    const float* __restrict__ fc2w, const float* __restrict__ fc2b,
    float* __restrict__ out, float* __restrict__ state, int t0, int tlen)
{
    const int b = blockIdx.x;
    const int g = threadIdx.x;
    __shared__ float hs[H];
    __shared__ float gates[G4];
    __shared__ float hbuf[64][132];
    __shared__ float fc1w_s[NFC * 132];
    __shared__ float hfcb[64 * NFC];
    __shared__ float fc2w_s[NFC];
    __shared__ float fc1b_s[NFC];
    float whh[H];
    const float4* W4 = (const float4*)(Whh1 + (size_t)g * H);
#pragma unroll
    for (int k4 = 0; k4 < H / 4; k4++) {
        float4 wv = W4[k4];
        whh[4 * k4 + 0] = wv.x; whh[4 * k4 + 1] = wv.y;
        whh[4 * k4 + 2] = wv.z; whh[4 * k4 + 3] = wv.w;
    }
    for (int i = g; i < NFC * H; i += 512) {
        int r = i >> 7, cidx = i & 127;
        fc1w_s[r * 132 + cidx] = fc1w[i];
    }
    if (g < NFC) { fc2w_s[g] = fc2w[g]; fc1b_s[g] = fc1b[g]; }
    float c = 0.f, h = 0.f;
    if (t0 > 0 && g < H) {
        c = state[b * H + g];
        h = state[BATCH * H + b * H + g];
    }
    if (g < H) hs[g] = h;
    float xgr = xg1[((size_t)b * tlen) * G4 + g];
    const float fc2bias = fc2b[0];
    __syncthreads();
    for (int tt = 0; tt < tlen; tt++) {
        float a0 = xgr, a1 = 0.f, a2 = 0.f, a3 = 0.f;
        if (tt + 1 < tlen) xgr = xg1[((size_t)b * tlen + tt + 1) * G4 + g];
        const float4* h4 = (const float4*)hs;
#pragma unroll
        for (int k4 = 0; k4 < H / 4; k4++) {
            float4 hv = h4[k4];
            a0 += whh[4 * k4 + 0] * hv.x;
            a1 += whh[4 * k4 + 1] * hv.y;
            a2 += whh[4 * k4 + 2] * hv.z;
            a3 += whh[4 * k4 + 3] * hv.w;
        }
        gates[g] = (a0 + a1) + (a2 + a3);
        __syncthreads();
        if (g < H) {
            float ig = sigf(gates[g]);
            float fg = sigf(gates[H + g]);
            float gg = tanh_fast(gates[2 * H + g]);
            float og = sigf(gates[3 * H + g]);
            c = fg * c + ig * gg;
            h = og * tanh_fast(c);
            hs[g] = h;
            hbuf[tt & 63][g] = h;
        }
        __syncthreads();
        if ((tt & 63) == 63) {
#pragma unroll
            for (int p = 0; p < 3; p++) {
                int task = p * 512 + g;
                if (task < 64 * NFC) {
                    int sidx = task / NFC;
                    int k = task - sidx * NFC;
                    float b0 = fc1b_s[k], b1 = 0.f, b2 = 0.f, b3 = 0.f;
                    const float4* hr = (const float4*)(&hbuf[sidx][0]);
                    const float4* wr = (const float4*)(&fc1w_s[k * 132]);
#pragma unroll
                    for (int k4 = 0; k4 < H / 4; k4++) {
                        float4 hv = hr[k4];
                        float4 wv = wr[k4];
                        b0 += wv.x * hv.x; b1 += wv.y * hv.y;
                        b2 += wv.z * hv.z; b3 += wv.w * hv.w;
                    }
                    hfcb[task] = tanh_fast((b0 + b1) + (b2 + b3));
                }
            }
            __syncthreads();
            if (g < 64) {
                float o = fc2bias;
#pragma unroll
                for (int k = 0; k < NFC; k++) o += fc2w_s[k] * hfcb[g * NFC + k];
                int tglob = t0 + tt - 63 + g;
                out[(size_t)b * TSEQ + tglob] = o;
            }
            __syncthreads();
        }
    }
    if (g < H) {
        state[b * H + g] = c;
        state[BATCH * H + b * H + g] = h;
    }
}

extern "C" void kernel_launch(void* const* d_in, const int* in_sizes, int n_in,
                              void* d_out, int out_size, void* d_ws, size_t ws_size,
                              hipStream_t stream) {
    const float* x    = (const float*)d_in[0];
    const float* Wih0 = (const float*)d_in[1];
    const float* Whh0 = (const float*)d_in[2];
    const float* bih0 = (const float*)d_in[3];
    const float* bhh0 = (const float*)d_in[4];
    const float* Wih1 = (const float*)d_in[5];
    const float* Whh1 = (const float*)d_in[6];
    const float* bih1 = (const float*)d_in[7];
    const float* bhh1 = (const float*)d_in[8];
    const float* fc1w = (const float*)d_in[9];
    const float* fc1b = (const float*)d_in[10];
    const float* fc2w = (const float*)d_in[11];
    const float* fc2b = (const float*)d_in[12];
    float* out = (float*)d_out;

    char* ws = (char*)d_ws;
    const size_t flag_region = 128 * 1024;                     // 4 x 64x64 ints = 64 KB used
    const size_t h0slot = (size_t)BATCH * CH * H * 4;          // 1 MB per ring depth
    const size_t xgslot = (size_t)BATCH * CH * G4 * 4;         // 4 MB per ring depth

    int R = 0;
    if (ws_size > flag_region)
        R = (int)((ws_size - flag_region) / (h0slot + xgslot));
    if (R > NCH) R = NCH;

    if (R >= 2) {
        int* flags  = (int*)ws;
        int* fAp    = flags;
        int* fAfree = flags + BATCH * NCH;
        int* fBp    = flags + 2 * BATCH * NCH;
        int* fBfree = flags + 3 * BATCH * NCH;
        float* h0ring = (float*)(ws + flag_region);
        float* xgring = (float*)(ws + flag_region + h0slot * (size_t)R);

        zero_flags<<<4, 512, 0, stream>>>(flags, 4 * BATCH * NCH);
        lstm_fused<<<192, 512, 0, stream>>>(x, Wih0, Whh0, bih0, bhh0,
                                            Wih1, Whh1, bih1, bhh1,
                                            fc1w, fc1b, fc2w, fc2b,
                                            h0ring, xgring,
                                            fAp, fAfree, fBp, fBfree,
                                            R, out);
    } else {
        // fallback: verified R4 three-kernel chunked path
        const size_t h0_bytes  = (size_t)BATCH * TSEQ * H * 4;
        const size_t mid_bytes = (size_t)2 * BATCH * H * 4;
        float* h0    = (float*)ws;
        float* state = (float*)(ws + h0_bytes);
        float* xg1   = (float*)(ws + h0_bytes + mid_bytes);
        int tlen = 64;
        const int cands[4] = {2048, 512, 128, 64};
        for (int i = 0; i < 4; i++) {
            size_t need = h0_bytes + mid_bytes + (size_t)BATCH * cands[i] * G4 * 4;
            if (ws_size >= need) { tlen = cands[i]; break; }
        }
        lstm0_scan<<<BATCH, 512, 0, stream>>>(x, Wih0, Whh0, bih0, bhh0, h0);
        const int nch = TSEQ / tlen;
        for (int ci = 0; ci < nch; ci++) {
            xg1_gemm<<<256, 512, 0, stream>>>(h0, Wih1, bih1, bhh1, xg1, ci * tlen, tlen);
            lstm1_scan<<<BATCH, 512, 0, stream>>>(Whh1, xg1, fc1w, fc1b, fc2w, fc2b,
                                                  out, state, ci * tlen, tlen);
        }
    }
}

// Round 12
// 3416.336 us; speedup vs baseline: 1.0271x; 1.0271x over previous
//
#include <hip/hip_runtime.h>
#include <hip/hip_bf16.h>

#define BATCH 64
#define TSEQ 2048
#define INF 9
#define H 128
#define G4 512
#define NFC 20
#define CH 64                 // pipeline chunk (timesteps)
#define NCH (TSEQ / CH)       // 32 chunks

__device__ __forceinline__ float sigf(float x) {
    return 1.0f / (1.0f + __expf(-x));
}
__device__ __forceinline__ float tanh_fast(float x) {
    // tanh(x) = 1 - 2/(e^{2x}+1); saturates correctly at +/-inf
    return 1.0f - 2.0f / (__expf(2.0f * x) + 1.0f);
}

// ---------------- flag helpers (agent scope, chunk-granular) ----------------
__device__ __forceinline__ void flag_release(int* f) {
    // call AFTER __syncthreads(): all block stores issued; fence + release
    // publishes them device-wide (cross-XCD per Guideline 16).
    if (threadIdx.x == 0) {
        __threadfence();
        __hip_atomic_store(f, 1, __ATOMIC_RELEASE, __HIP_MEMORY_SCOPE_AGENT);
    }
}
__device__ __forceinline__ void flag_acquire(int* f) {
    if (threadIdx.x == 0) {
        while (__hip_atomic_load(f, __ATOMIC_ACQUIRE, __HIP_MEMORY_SCOPE_AGENT) == 0)
            __builtin_amdgcn_s_sleep(32);
        __threadfence();
    }
    __syncthreads();
}

__global__ __launch_bounds__(512) void zero_flags(int* flags, int n) {
    for (int i = threadIdx.x; i < n; i += 512) flags[i] = 0;
}

// ================= fused 3-stage ring pipeline =================
// blocks [0,64):   A = lstm0 scan (batch row b) -> h0ring
// blocks [64,128): B = xg1 gemv  (batch row b)  h0ring -> xgring
// blocks [128,192):C = lstm1 scan + head        xgring -> out
// Ring slots: slot = ci % R. Flags: fA (A->B ready), fAfree (B consumed h0
// slot), fB (B->C ready), fBfree (C consumed xg slot).
__global__ __launch_bounds__(512) void lstm_fused(
    const float* __restrict__ x,
    const float* __restrict__ Wih0, const float* __restrict__ Whh0,
    const float* __restrict__ bih0, const float* __restrict__ bhh0,
    const float* __restrict__ Wih1, const float* __restrict__ Whh1,
    const float* __restrict__ bih1, const float* __restrict__ bhh1,
    const float* __restrict__ fc1w, const float* __restrict__ fc1b,
    const float* __restrict__ fc2w, const float* __restrict__ fc2b,
    float* __restrict__ h0ring, float* __restrict__ xgring,
    int* __restrict__ fA, int* __restrict__ fAfree,
    int* __restrict__ fB, int* __restrict__ fBfree,
    int R, float* __restrict__ out)
{
    __shared__ float hs[H];
    __shared__ float gates[G4];
    __shared__ float hsB[2][H];
    __shared__ float hbuf[64][132];
    __shared__ float fc1w_s[NFC * 132];
    __shared__ float hfcb[64 * NFC];
    __shared__ float fc2w_s[NFC];
    __shared__ float fc1b_s[NFC];

    const int role = blockIdx.x >> 6;
    const int b    = blockIdx.x & 63;
    const int g    = threadIdx.x;

    if (role == 0) {
        // ---------------- A: layer-0 scan (R4-verified body) ----------------
        float wih[INF], whh[H];
#pragma unroll
        for (int k = 0; k < INF; k++) wih[k] = Wih0[(size_t)g * INF + k];
        const float4* W4 = (const float4*)(Whh0 + (size_t)g * H);
#pragma unroll
        for (int k4 = 0; k4 < H / 4; k4++) {
            float4 wv = W4[k4];
            whh[4 * k4 + 0] = wv.x; whh[4 * k4 + 1] = wv.y;
            whh[4 * k4 + 2] = wv.z; whh[4 * k4 + 3] = wv.w;
        }
        const float bias = bih0[g] + bhh0[g];

        float c = 0.f;
        if (g < H) hs[g] = 0.f;

        const float* xb = x + (size_t)b * TSEQ * INF;
        float xr[INF];
#pragma unroll
        for (int k = 0; k < INF; k++) xr[k] = xb[k];
        __syncthreads();

        for (int ci = 0; ci < NCH; ci++) {
            if (ci >= R) flag_acquire(&fAfree[b * NCH + ci - R]);
            const int slot = ci % R;
            float* h0s = h0ring + ((size_t)slot * BATCH + b) * CH * H;

            for (int tt = 0; tt < CH; tt++) {
                const int t = ci * CH + tt;
                float a0 = bias, a1 = 0.f, a2 = 0.f, a3 = 0.f;
#pragma unroll
                for (int k = 0; k < INF; k++) a0 += wih[k] * xr[k];
                if (t + 1 < TSEQ) {
                    const float* xn = xb + (size_t)(t + 1) * INF;
#pragma unroll
                    for (int k = 0; k < INF; k++) xr[k] = xn[k];
                }
                const float4* h4 = (const float4*)hs;
#pragma unroll
                for (int k4 = 0; k4 < H / 4; k4++) {
                    float4 hv = h4[k4];
                    a0 += whh[4 * k4 + 0] * hv.x;
                    a1 += whh[4 * k4 + 1] * hv.y;
                    a2 += whh[4 * k4 + 2] * hv.z;
                    a3 += whh[4 * k4 + 3] * hv.w;
                }
                gates[g] = (a0 + a1) + (a2 + a3);
                __syncthreads();
                if (g < H) {
                    float ig = sigf(gates[g]);
                    float fg = sigf(gates[H + g]);
                    float gg = tanh_fast(gates[2 * H + g]);
                    float og = sigf(gates[3 * H + g]);
                    c = fg * c + ig * gg;
                    float h = og * tanh_fast(c);
                    hs[g] = h;
                    h0s[(size_t)tt * H + g] = h;
                }
                __syncthreads();
            }
            flag_release(&fA[b * NCH + ci]);
        }
    } else if (role == 1) {
        // ---------------- B: xg = h0 @ Wih1^T + bias (R4 per-row order) ----------------
        const float bias = bih1[g] + bhh1[g];
        const float4* W4 = (const float4*)(Wih1 + (size_t)g * H);

        for (int ci = 0; ci < NCH; ci++) {
            flag_acquire(&fA[b * NCH + ci]);
            if (ci >= R) flag_acquire(&fBfree[b * NCH + ci - R]);
            const int slot = ci % R;
            const float* h0s = h0ring + ((size_t)slot * BATCH + b) * CH * H;
            float* xgs = xgring + ((size_t)slot * BATCH + b) * CH * G4;

            for (int r2 = 0; r2 < CH / 2; r2++) {
                const int tt = 2 * r2;
                if (g < H)
                    hsB[0][g] = h0s[(size_t)tt * H + g];
                else if (g < 2 * H)
                    hsB[1][g - H] = h0s[(size_t)(tt + 1) * H + (g - H)];
                __syncthreads();
                float a0 = bias, a1 = 0.f, a2 = 0.f, a3 = 0.f;
                float c0 = bias, c1 = 0.f, c2 = 0.f, c3 = 0.f;
                const float4* h40 = (const float4*)hsB[0];
                const float4* h41 = (const float4*)hsB[1];
#pragma unroll
                for (int k4 = 0; k4 < H / 4; k4++) {
                    float4 wv = W4[k4];     // streamed once, serves both rows
                    float4 hv0 = h40[k4];
                    float4 hv1 = h41[k4];
                    a0 += wv.x * hv0.x; a1 += wv.y * hv0.y;
                    a2 += wv.z * hv0.z; a3 += wv.w * hv0.w;
                    c0 += wv.x * hv1.x; c1 += wv.y * hv1.y;
                    c2 += wv.z * hv1.z; c3 += wv.w * hv1.w;
                }
                xgs[(size_t)tt * G4 + g]       = (a0 + a1) + (a2 + a3);
                xgs[(size_t)(tt + 1) * G4 + g] = (c0 + c1) + (c2 + c3);
                __syncthreads();
            }
            flag_release(&fAfree[b * NCH + ci]);
            flag_release(&fB[b * NCH + ci]);
        }
    } else {
        // ---------------- C: layer-1 scan + fused head (R4-verified body) ----------------
        float whh[H];
        const float4* W4 = (const float4*)(Whh1 + (size_t)g * H);
#pragma unroll
        for (int k4 = 0; k4 < H / 4; k4++) {
            float4 wv = W4[k4];
            whh[4 * k4 + 0] = wv.x; whh[4 * k4 + 1] = wv.y;
            whh[4 * k4 + 2] = wv.z; whh[4 * k4 + 3] = wv.w;
        }
        for (int i = g; i < NFC * H; i += 512) {
            int r = i >> 7, cidx = i & 127;
            fc1w_s[r * 132 + cidx] = fc1w[i];
        }
        if (g < NFC) { fc2w_s[g] = fc2w[g]; fc1b_s[g] = fc1b[g]; }

        float c = 0.f, h = 0.f;
        if (g < H) hs[g] = 0.f;
        const float fc2bias = fc2b[0];
        __syncthreads();

        for (int ci = 0; ci < NCH; ci++) {
            flag_acquire(&fB[b * NCH + ci]);
            const int slot = ci % R;
            const float* xgs = xgring + ((size_t)slot * BATCH + b) * CH * G4;
            float xgr = xgs[g];

            for (int tt = 0; tt < CH; tt++) {
                float a0 = xgr, a1 = 0.f, a2 = 0.f, a3 = 0.f;
                if (tt + 1 < CH) xgr = xgs[(size_t)(tt + 1) * G4 + g];
                const float4* h4 = (const float4*)hs;
#pragma unroll
                for (int k4 = 0; k4 < H / 4; k4++) {
                    float4 hv = h4[k4];
                    a0 += whh[4 * k4 + 0] * hv.x;
                    a1 += whh[4 * k4 + 1] * hv.y;
                    a2 += whh[4 * k4 + 2] * hv.z;
                    a3 += whh[4 * k4 + 3] * hv.w;
                }
                gates[g] = (a0 + a1) + (a2 + a3);
                __syncthreads();
                if (g < H) {
                    float ig = sigf(gates[g]);
                    float fg = sigf(gates[H + g]);
                    float gg = tanh_fast(gates[2 * H + g]);
                    float og = sigf(gates[3 * H + g]);
                    c = fg * c + ig * gg;
                    h = og * tanh_fast(c);
                    hs[g] = h;
                    hbuf[tt][g] = h;
                }
                __syncthreads();

                if (tt == CH - 1) {
#pragma unroll
                    for (int p = 0; p < 3; p++) {
                        int task = p * 512 + g;
                        if (task < 64 * NFC) {
                            int sidx = task / NFC;
                            int k = task - sidx * NFC;
                            float b0 = fc1b_s[k], b1 = 0.f, b2 = 0.f, b3 = 0.f;
                            const float4* hr = (const float4*)(&hbuf[sidx][0]);
                            const float4* wr = (const float4*)(&fc1w_s[k * 132]);
#pragma unroll
                            for (int k4 = 0; k4 < H / 4; k4++) {
                                float4 hv = hr[k4];
                                float4 wv = wr[k4];
                                b0 += wv.x * hv.x; b1 += wv.y * hv.y;
                                b2 += wv.z * hv.z; b3 += wv.w * hv.w;
                            }
                            hfcb[task] = tanh_fast((b0 + b1) + (b2 + b3));
                        }
                    }
                    __syncthreads();
                    if (g < 64) {
                        float o = fc2bias;
#pragma unroll
                        for (int k = 0; k < NFC; k++) o += fc2w_s[k] * hfcb[g * NFC + k];
                        out[(size_t)b * TSEQ + ci * CH + g] = o;
                    }
                    __syncthreads();
                }
            }
            flag_release(&fBfree[b * NCH + ci]);
        }
    }
}

// ================= fallback (verified R4 three-kernel path) =================
__global__ __launch_bounds__(512, 2) void lstm0_scan(
    const float* __restrict__ x, const float* __restrict__ Wih,
    const float* __restrict__ Whh, const float* __restrict__ bih,
    const float* __restrict__ bhh, float* __restrict__ h0out)
{
    const int b = blockIdx.x;
    const int g = threadIdx.x;
    __shared__ float hs[H];
    __shared__ float gates[G4];
    float wih[INF], whh[H];
#pragma unroll
    for (int k = 0; k < INF; k++) wih[k] = Wih[(size_t)g * INF + k];
    const float4* W4 = (const float4*)(Whh + (size_t)g * H);
#pragma unroll
    for (int k4 = 0; k4 < H / 4; k4++) {
        float4 wv = W4[k4];
        whh[4 * k4 + 0] = wv.x; whh[4 * k4 + 1] = wv.y;
        whh[4 * k4 + 2] = wv.z; whh[4 * k4 + 3] = wv.w;
    }
    const float bias = bih[g] + bhh[g];
    float c = 0.f;
    if (g < H) hs[g] = 0.f;
    const float* xb = x + (size_t)b * TSEQ * INF;
    float xr[INF];
#pragma unroll
    for (int k = 0; k < INF; k++) xr[k] = xb[k];
    __syncthreads();
    for (int t = 0; t < TSEQ; t++) {
        float a0 = bias, a1 = 0.f, a2 = 0.f, a3 = 0.f;
#pragma unroll
        for (int k = 0; k < INF; k++) a0 += wih[k] * xr[k];
        if (t + 1 < TSEQ) {
            const float* xn = xb + (size_t)(t + 1) * INF;
#pragma unroll
            for (int k = 0; k < INF; k++) xr[k] = xn[k];
        }
        const float4* h4 = (const float4*)hs;
#pragma unroll
        for (int k4 = 0; k4 < H / 4; k4++) {
            float4 hv = h4[k4];
            a0 += whh[4 * k4 + 0] * hv.x;
            a1 += whh[4 * k4 + 1] * hv.y;
            a2 += whh[4 * k4 + 2] * hv.z;
            a3 += whh[4 * k4 + 3] * hv.w;
        }
        gates[g] = (a0 + a1) + (a2 + a3);
        __syncthreads();
        if (g < H) {
            float ig = sigf(gates[g]);
            float fg = sigf(gates[H + g]);
            float gg = tanh_fast(gates[2 * H + g]);
            float og = sigf(gates[3 * H + g]);
            c = fg * c + ig * gg;
            float h = og * tanh_fast(c);
            hs[g] = h;
            h0out[((size_t)b * TSEQ + t) * H + g] = h;
        }
        __syncthreads();
    }
}

__global__ __launch_bounds__(512, 2) void xg1_gemm(
    const float* __restrict__ h0, const float* __restrict__ Wih1,
    const float* __restrict__ bih, const float* __restrict__ bhh,
    float* __restrict__ xg1, int t0, int tlen)
{
    const int b = blockIdx.x >> 2;
    const int s = blockIdx.x & 3;
    const int g = threadIdx.x;
    const int rows = tlen >> 2;
    const int tstart = t0 + s * rows;
    float w[H];
    const float4* W4 = (const float4*)(Wih1 + (size_t)g * H);
#pragma unroll
    for (int k4 = 0; k4 < H / 4; k4++) {
        float4 wv = W4[k4];
        w[4 * k4 + 0] = wv.x; w[4 * k4 + 1] = wv.y;
        w[4 * k4 + 2] = wv.z; w[4 * k4 + 3] = wv.w;
    }
    const float bias = bih[g] + bhh[g];
    __shared__ float hs[2][H];
    if (g < H) hs[0][g] = h0[((size_t)b * TSEQ + tstart) * H + g];
    __syncthreads();
    for (int r = 0; r < rows; r++) {
        int buf = r & 1;
        if (g < H && (r + 1) < rows)
            hs[buf ^ 1][g] = h0[((size_t)b * TSEQ + tstart + r + 1) * H + g];
        float a0 = bias, a1 = 0.f, a2 = 0.f, a3 = 0.f;
        const float4* h4 = (const float4*)hs[buf];
#pragma unroll
        for (int k4 = 0; k4 < H / 4; k4++) {
            float4 hv = h4[k4];
            a0 += w[4 * k4 + 0] * hv.x;
            a1 += w[4 * k4 + 1] * hv.y;
            a2 += w[4 * k4 + 2] * hv.z;
            a3 += w[4 * k4 + 3] * hv.w;
        }
        xg1[((size_t)b * tlen + (size_t)(s * rows + r)) * G4 + g] = (a0 + a1) + (a2 + a3);
        __syncthreads();
    }
}

__global__ __launch_bounds__(512, 2) void lstm1_scan(
    const float* __restrict__ Whh1, const float* __restrict__ xg1,
    const float* __restrict__ fc1w, const float* __restrict__ fc1b,
    const float* __restrict__ fc2w, const float* __restrict__ fc2b,
    float* __restrict__ out, float* __restrict__ state, int t0, int tlen)
{
    const int b = blockIdx.x;
    const int g = threadIdx.x;
    __shared__ float hs[H];
    __shared__ float gates[G4];
    __shared__ float hbuf[64][132];
    __shared__ float fc1w_s[NFC * 132];
    __shared__ float hfcb[64 * NFC];
    __shared__ float fc2w_s[NFC];
    __shared__ float fc1b_s[NFC];
    float whh[H];
    const float4* W4 = (const float4*)(Whh1 + (size_t)g * H);
#pragma unroll
    for (int k4 = 0; k4 < H / 4; k4++) {
        float4 wv = W4[k4];
        whh[4 * k4 + 0] = wv.x; whh[4 * k4 + 1] = wv.y;
        whh[4 * k4 + 2] = wv.z; whh[4 * k4 + 3] = wv.w;
    }
    for (int i = g; i < NFC * H; i += 512) {
        int r = i >> 7, cidx = i & 127;
        fc1w_s[r * 132 + cidx] = fc1w[i];
    }
    if (g < NFC) { fc2w_s[g] = fc2w[g]; fc1b_s[g] = fc1b[g]; }
    float c = 0.f, h = 0.f;
    if (t0 > 0 && g < H) {
        c = state[b * H + g];
        h = state[BATCH * H + b * H + g];
    }
    if (g < H) hs[g] = h;
    float xgr = xg1[((size_t)b * tlen) * G4 + g];
    const float fc2bias = fc2b[0];
    __syncthreads();
    for (int tt = 0; tt < tlen; tt++) {
        float a0 = xgr, a1 = 0.f, a2 = 0.f, a3 = 0.f;
        if (tt + 1 < tlen) xgr = xg1[((size_t)b * tlen + tt + 1) * G4 + g];
        const float4* h4 = (const float4*)hs;
#pragma unroll
        for (int k4 = 0; k4 < H / 4; k4++) {
            float4 hv = h4[k4];
            a0 += whh[4 * k4 + 0] * hv.x;
            a1 += whh[4 * k4 + 1] * hv.y;
            a2 += whh[4 * k4 + 2] * hv.z;
            a3 += whh[4 * k4 + 3] * hv.w;
        }
        gates[g] = (a0 + a1) + (a2 + a3);
        __syncthreads();
        if (g < H) {
            float ig = sigf(gates[g]);
            float fg = sigf(gates[H + g]);
            float gg = tanh_fast(gates[2 * H + g]);
            float og = sigf(gates[3 * H + g]);
            c = fg * c + ig * gg;
            h = og * tanh_fast(c);
            hs[g] = h;
            hbuf[tt & 63][g] = h;
        }
        __syncthreads();
        if ((tt & 63) == 63) {
#pragma unroll
            for (int p = 0; p < 3; p++) {
                int task = p * 512 + g;
                if (task < 64 * NFC) {
                    int sidx = task / NFC;
                    int k = task - sidx * NFC;
                    float b0 = fc1b_s[k], b1 = 0.f, b2 = 0.f, b3 = 0.f;
                    const float4* hr = (const float4*)(&hbuf[sidx][0]);
                    const float4* wr = (const float4*)(&fc1w_s[k * 132]);
#pragma unroll
                    for (int k4 = 0; k4 < H / 4; k4++) {
                        float4 hv = hr[k4];
                        float4 wv = wr[k4];
                        b0 += wv.x * hv.x; b1 += wv.y * hv.y;
                        b2 += wv.z * hv.z; b3 += wv.w * hv.w;
                    }
                    hfcb[task] = tanh_fast((b0 + b1) + (b2 + b3));
                }
            }
            __syncthreads();
            if (g < 64) {
                float o = fc2bias;
#pragma unroll
                for (int k = 0; k < NFC; k++) o += fc2w_s[k] * hfcb[g * NFC + k];
                int tglob = t0 + tt - 63 + g;
                out[(size_t)b * TSEQ + tglob] = o;
            }
            __syncthreads();
        }
    }
    if (g < H) {
        state[b * H + g] = c;
        state[BATCH * H + b * H + g] = h;
    }
}

extern "C" void kernel_launch(void* const* d_in, const int* in_sizes, int n_in,
                              void* d_out, int out_size, void* d_ws, size_t ws_size,
                              hipStream_t stream) {
    const float* x    = (const float*)d_in[0];
    const float* Wih0 = (const float*)d_in[1];
    const float* Whh0 = (const float*)d_in[2];
    const float* bih0 = (const float*)d_in[3];
    const float* bhh0 = (const float*)d_in[4];
    const float* Wih1 = (const float*)d_in[5];
    const float* Whh1 = (const float*)d_in[6];
    const float* bih1 = (const float*)d_in[7];
    const float* bhh1 = (const float*)d_in[8];
    const float* fc1w = (const float*)d_in[9];
    const float* fc1b = (const float*)d_in[10];
    const float* fc2w = (const float*)d_in[11];
    const float* fc2b = (const float*)d_in[12];
    float* out = (float*)d_out;

    char* ws = (char*)d_ws;
    const size_t flag_region = 64 * 1024;                      // 4 arrays x 64x32 ints = 32 KB
    const size_t h0slot = (size_t)BATCH * CH * H * 4;          // 2 MB per ring depth
    const size_t xgslot = (size_t)BATCH * CH * G4 * 4;         // 8 MB per ring depth

    int R = 0;
    if (ws_size > flag_region)
        R = (int)((ws_size - flag_region) / (h0slot + xgslot));
    if (R > NCH) R = NCH;

    if (R >= 2) {
        // fused ring pipeline: A (64) | B (64) | C (64) blocks, all co-resident
        int* flags  = (int*)ws;
        int* fAp    = flags;
        int* fAfree = flags + BATCH * NCH;
        int* fBp    = flags + 2 * BATCH * NCH;
        int* fBfree = flags + 3 * BATCH * NCH;
        float* h0ring = (float*)(ws + flag_region);
        float* xgring = (float*)(ws + flag_region + h0slot * (size_t)R);

        zero_flags<<<1, 512, 0, stream>>>(flags, 4 * BATCH * NCH);
        lstm_fused<<<192, 512, 0, stream>>>(x, Wih0, Whh0, bih0, bhh0,
                                            Wih1, Whh1, bih1, bhh1,
                                            fc1w, fc1b, fc2w, fc2b,
                                            h0ring, xgring,
                                            fAp, fAfree, fBp, fBfree,
                                            R, out);
    } else {
        // fallback: verified R4 three-kernel chunked path
        const size_t h0_bytes  = (size_t)BATCH * TSEQ * H * 4;
        const size_t mid_bytes = (size_t)2 * BATCH * H * 4;
        float* h0    = (float*)ws;
        float* state = (float*)(ws + h0_bytes);
        float* xg1   = (float*)(ws + h0_bytes + mid_bytes);
        int tlen = 64;
        const int cands[4] = {2048, 512, 128, 64};
        for (int i = 0; i < 4; i++) {
            size_t need = h0_bytes + mid_bytes + (size_t)BATCH * cands[i] * G4 * 4;
            if (ws_size >= need) { tlen = cands[i]; break; }
        }
        lstm0_scan<<<BATCH, 512, 0, stream>>>(x, Wih0, Whh0, bih0, bhh0, h0);
        const int nch = TSEQ / tlen;
        for (int ci = 0; ci < nch; ci++) {
            xg1_gemm<<<256, 512, 0, stream>>>(h0, Wih1, bih1, bhh1, xg1, ci * tlen, tlen);
            lstm1_scan<<<BATCH, 512, 0, stream>>>(Whh1, xg1, fc1w, fc1b, fc2w, fc2b,
                                                  out, state, ci * tlen, tlen);
        }
    }
}